// Round 1
// baseline (2938.319 us; speedup 1.0000x reference)
//
#include <hip/hip_runtime.h>

// LSTM, B=512 batches x T=1024 steps, H=100, input_size=1.
// Persistent-RNN design: one block per batch; W_hh rows live in VGPRs
// (thread r holds row r, 100 fp32 regs); h broadcast via LDS each step.
// Batches are independent -> no inter-block communication.

#define HID 100
#define FOURH 400
#define TLEN 1024
#define BLOCK 448   // 7 waves; threads 0..399 own gate rows

__global__ __launch_bounds__(BLOCK) void lstm_persist(
    const float* __restrict__ input,   // [B, T]
    const float* __restrict__ W_ih,    // [4H] (input_size==1)
    const float* __restrict__ W_hh,    // [4H, H] row-major
    const float* __restrict__ b_ih,    // [4H]
    const float* __restrict__ b_hh,    // [4H]
    const float* __restrict__ W_out,   // [H]
    const float* __restrict__ b_out,   // [1]
    float* __restrict__ out)           // [B, T]
{
    const int b   = blockIdx.x;
    const int tid = threadIdx.x;

    __shared__ float4 h4_s[HID / 4];      // h[100] as 25 float4 (16B-aligned)
    __shared__ float  gates_s[FOURH];
    __shared__ float  in_s[TLEN];

    float* h_s = (float*)h4_s;

    // Stage this batch's input row (4 KB) into LDS, coalesced.
    for (int i = tid; i < TLEN; i += BLOCK)
        in_s[i] = input[b * TLEN + i];

    // Pin this thread's recurrent-weight row in registers.
    float w[HID];
    float wih = 0.f, bias = 0.f;
    if (tid < FOURH) {
        // row offset = tid*100 floats = tid*400 bytes; 400 % 16 == 0 -> float4 ok
        const float4* wrow = (const float4*)(W_hh + tid * HID);
        #pragma unroll
        for (int k = 0; k < HID / 4; ++k) {
            float4 v = wrow[k];
            w[4 * k + 0] = v.x; w[4 * k + 1] = v.y;
            w[4 * k + 2] = v.z; w[4 * k + 3] = v.w;
        }
        wih  = W_ih[tid];
        bias = b_ih[tid] + b_hh[tid];
    }

    // Output-projection weights for wave 0's reduction.
    float wo0 = 0.f, wo1 = 0.f, bo = 0.f;
    if (tid < 64) {
        wo0 = W_out[tid];
        if (tid < HID - 64) wo1 = W_out[64 + tid];   // lanes 0..35 cover h[64..99]
        bo = b_out[0];
    }

    float c = 0.f;                 // cell state, register-resident in thread tid<100
    if (tid < HID) h_s[tid] = 0.f; // h0 = 0
    __syncthreads();

    float* outp = out + b * TLEN;

    for (int t = 0; t < TLEN; ++t) {
        // ---- Phase A: gates[r] = x*W_ih[r] + (b_ih+b_hh)[r] + dot(h, W_hh[r,:])
        if (tid < FOURH) {
            float base = fmaf(in_s[t], wih, bias);
            float a0 = 0.f, a1 = 0.f, a2 = 0.f, a3 = 0.f;  // 4 chains: hide FMA latency
            #pragma unroll
            for (int k = 0; k < HID / 4; ++k) {
                float4 hv = h4_s[k];           // wave-uniform address -> LDS broadcast
                a0 = fmaf(hv.x, w[4 * k + 0], a0);
                a1 = fmaf(hv.y, w[4 * k + 1], a1);
                a2 = fmaf(hv.z, w[4 * k + 2], a2);
                a3 = fmaf(hv.w, w[4 * k + 3], a3);
            }
            gates_s[tid] = base + ((a0 + a1) + (a2 + a3));
        }
        __syncthreads();

        // ---- Phase B: pointwise LSTM cell (threads 0..99)
        if (tid < HID) {
            float ig = gates_s[tid];
            float fg = gates_s[HID + tid];
            float gg = gates_s[2 * HID + tid];
            float og = gates_s[3 * HID + tid];
            float is = 1.f / (1.f + __expf(-ig));
            float fs = 1.f / (1.f + __expf(-fg));
            float gt = tanhf(gg);
            float os = 1.f / (1.f + __expf(-og));
            c = fmaf(fs, c, is * gt);
            h_s[tid] = os * tanhf(c);
        }
        __syncthreads();

        // ---- Phase C: out[t] = dot(h, W_out) + b_out  (wave 0 only; off critical path)
        if (tid < 64) {
            float p = h_s[tid] * wo0;
            if (tid < HID - 64) p = fmaf(h_s[64 + tid], wo1, p);
            #pragma unroll
            for (int off = 32; off > 0; off >>= 1)
                p += __shfl_down(p, off);
            if (tid == 0) outp[t] = p + bo;
        }
        // no barrier needed: h_s is next written only after the Phase-A barrier
    }
}

extern "C" void kernel_launch(void* const* d_in, const int* in_sizes, int n_in,
                              void* d_out, int out_size, void* d_ws, size_t ws_size,
                              hipStream_t stream) {
    const float* input = (const float*)d_in[0];
    const float* W_ih  = (const float*)d_in[1];
    const float* W_hh  = (const float*)d_in[2];
    const float* b_ih  = (const float*)d_in[3];
    const float* b_hh  = (const float*)d_in[4];
    const float* W_out = (const float*)d_in[5];
    const float* b_out = (const float*)d_in[6];
    float* out = (float*)d_out;

    const int B = in_sizes[0] / TLEN;  // 512
    lstm_persist<<<B, BLOCK, 0, stream>>>(input, W_ih, W_hh, b_ih, b_hh,
                                          W_out, b_out, out);
}

// Round 2
// 2078.497 us; speedup vs baseline: 1.4137x; 1.4137x over previous
//
#include <hip/hip_runtime.h>

// LSTM, B=512 x T=1024, H=100, input_size=1.
// Persistent-RNN: one block per 2 batches (grid=256 -> 1 block/CU, single pass).
// Thread r<400 holds W_hh row r in VGPRs (25 float4); h broadcast via LDS.
// __launch_bounds__(448,1): allow full VGPR budget -> no scratch spill (R1 bug:
// default occupancy heuristic at launch_bounds(448) capped VGPR=84 and spilled
// the 100-float weight array to scratch).

#define HID   100
#define H4    25     // HID/4
#define FOURH 400
#define TLEN  1024
#define BLOCK 448    // 7 waves; threads 0..399 own gate rows

__global__ __launch_bounds__(BLOCK, 1) void lstm_persist2(
    const float* __restrict__ input,   // [B, T]
    const float* __restrict__ W_ih,    // [4H]
    const float* __restrict__ W_hh,    // [4H, H]
    const float* __restrict__ b_ih,    // [4H]
    const float* __restrict__ b_hh,    // [4H]
    const float* __restrict__ W_out,   // [H]
    const float* __restrict__ b_out,   // [1]
    float* __restrict__ out)           // [B, T]
{
    const int b0  = blockIdx.x * 2;    // this block owns batches b0, b0+1
    const int tid = threadIdx.x;

    __shared__ float4 h0_4[H4];        // h for batch b0 (16B-aligned)
    __shared__ float4 h1_4[H4];        // h for batch b0+1
    __shared__ float  g0_s[FOURH];
    __shared__ float  g1_s[FOURH];
    __shared__ float  in0_s[TLEN];
    __shared__ float  in1_s[TLEN];

    // Stage both input rows (8 KB), coalesced.
    for (int i = tid; i < TLEN; i += BLOCK) {
        in0_s[i] = input[(b0 + 0) * TLEN + i];
        in1_s[i] = input[(b0 + 1) * TLEN + i];
    }

    // Pin this thread's recurrent-weight row in registers — UNCONDITIONAL
    // load (clamped row) so the array promotes cleanly to VGPRs.
    const int r = (tid < FOURH) ? tid : 0;
    float4 w[H4];
    {
        const float4* wrow = (const float4*)(W_hh + r * HID);  // 400 B rows: 16B-aligned
        #pragma unroll
        for (int k = 0; k < H4; ++k) w[k] = wrow[k];
    }
    const float wih  = W_ih[r];
    const float bias = b_ih[r] + b_hh[r];

    // Output-projection weights for the two reduction waves (tid<128).
    float wo0 = 0.f, wo1 = 0.f, bo = 0.f;
    if (tid < 128) {
        const int l = tid & 63;
        wo0 = W_out[l < HID ? l : 0] * (l < HID ? 1.f : 0.f);
        wo1 = (l < HID - 64) ? W_out[64 + l] : 0.f;
        bo  = b_out[0];
    }

    float c = 0.f;                       // cell state (tid<200: one per batch-element)
    if (tid < HID) { ((float*)h0_4)[tid] = 0.f; ((float*)h1_4)[tid] = 0.f; }
    __syncthreads();

    for (int t = 0; t < TLEN; ++t) {
        // ---- Phase A: dual-batch dot products against register-resident row
        if (tid < FOURH) {
            float base0 = fmaf(in0_s[t], wih, bias);
            float base1 = fmaf(in1_s[t], wih, bias);
            float a0 = 0.f, a1 = 0.f, a2 = 0.f, a3 = 0.f;
            float d0 = 0.f, d1 = 0.f, d2 = 0.f, d3 = 0.f;
            #pragma unroll
            for (int k = 0; k < H4; ++k) {
                float4 ha = h0_4[k];     // wave-uniform address -> LDS broadcast
                float4 hb = h1_4[k];
                float4 wk = w[k];
                a0 = fmaf(ha.x, wk.x, a0);
                a1 = fmaf(ha.y, wk.y, a1);
                a2 = fmaf(ha.z, wk.z, a2);
                a3 = fmaf(ha.w, wk.w, a3);
                d0 = fmaf(hb.x, wk.x, d0);
                d1 = fmaf(hb.y, wk.y, d1);
                d2 = fmaf(hb.z, wk.z, d2);
                d3 = fmaf(hb.w, wk.w, d3);
            }
            g0_s[tid] = base0 + ((a0 + a1) + (a2 + a3));
            g1_s[tid] = base1 + ((d0 + d1) + (d2 + d3));
        }
        __syncthreads();

        // ---- Phase B: pointwise LSTM cell, 200 threads (100 per batch)
        if (tid < 2 * HID) {
            const int   j  = (tid < HID) ? tid : tid - HID;
            const float* g = (tid < HID) ? g0_s : g1_s;
            float*       h = (tid < HID) ? (float*)h0_4 : (float*)h1_4;
            float ig = g[j];
            float fg = g[HID + j];
            float gg = g[2 * HID + j];
            float og = g[3 * HID + j];
            float is = 1.f / (1.f + __expf(-ig));
            float fs = 1.f / (1.f + __expf(-fg));
            float os = 1.f / (1.f + __expf(-og));
            float gt = 1.f - 2.f / (__expf(2.f * gg) + 1.f);   // stable tanh
            c = fmaf(fs, c, is * gt);
            float th = 1.f - 2.f / (__expf(2.f * c) + 1.f);
            h[j] = os * th;
        }
        __syncthreads();

        // ---- Phase C: out[t] = dot(h, W_out)+b_out; wave0->batch0, wave1->batch1
        if (tid < 128) {
            const int    l = tid & 63;
            const float* h = (tid < 64) ? (const float*)h0_4 : (const float*)h1_4;
            float p = (l < HID) ? h[l] * wo0 : 0.f;
            if (l < HID - 64) p = fmaf(h[64 + l], wo1, p);
            #pragma unroll
            for (int off = 32; off > 0; off >>= 1)
                p += __shfl_down(p, off);
            if (l == 0) out[(b0 + (tid >> 6)) * TLEN + t] = p + bo;
        }
        // No barrier here: h is re-written only after the next Phase-A barrier,
        // so Phase C(t) reads race only with Phase A(t+1) reads (both read-only).
    }
}

extern "C" void kernel_launch(void* const* d_in, const int* in_sizes, int n_in,
                              void* d_out, int out_size, void* d_ws, size_t ws_size,
                              hipStream_t stream) {
    const float* input = (const float*)d_in[0];
    const float* W_ih  = (const float*)d_in[1];
    const float* W_hh  = (const float*)d_in[2];
    const float* b_ih  = (const float*)d_in[3];
    const float* b_hh  = (const float*)d_in[4];
    const float* W_out = (const float*)d_in[5];
    const float* b_out = (const float*)d_in[6];
    float* out = (float*)d_out;

    const int B = in_sizes[0] / TLEN;  // 512
    lstm_persist2<<<B / 2, BLOCK, 0, stream>>>(input, W_ih, W_hh, b_ih, b_hh,
                                               W_out, b_out, out);
}